// Round 4
// baseline (333.934 us; speedup 1.0000x reference)
//
#include <hip/hip_runtime.h>
#include <hip/hip_cooperative_groups.h>

namespace cg = cooperative_groups;

typedef unsigned short ushort_t;
typedef __attribute__((ext_vector_type(8))) short short8;
typedef __attribute__((ext_vector_type(4))) short short4v;
typedef __attribute__((ext_vector_type(4))) float f32x4;
typedef __attribute__((ext_vector_type(4))) unsigned short ushort4v;
typedef __attribute__((ext_vector_type(8))) unsigned short ushort8v;

#define S_LEN 2048
#define D_MODEL 1024
#define NH 16
#define NKV 4
#define HD 64

// fp32 -> bf16 round-to-nearest-even
__device__ __forceinline__ ushort_t f2bf(float f) {
    unsigned u = __float_as_uint(f);
    u += 0x7fffu + ((u >> 16) & 1u);
    return (ushort_t)(u >> 16);
}

// async global->LDS, 16B/lane; LDS base wave-uniform, HW scatters lane*16
__device__ __forceinline__ void cp16(void* lds, const void* g) {
    __builtin_amdgcn_global_load_lds(
        (__attribute__((address_space(1))) void*)g,
        (__attribute__((address_space(3))) void*)lds, 16, 0, 0);
}

// ---------------------------------------------------------------------------
// Single cooperative kernel: 4 phases separated by grid.sync().
//   phase 0: prep (x cast + W transposes), 896 units grid-strided
//   phase 1: QKV gemm + RoPE, 384 units (bid<384)
//   phase 2: flash attention (R3 in-register-P version), 512 units
//   phase 3: output projection, 512 units
// 512 blocks x 256 thr, 64 KB LDS -> exactly 2 blocks/CU co-resident.
// Removes 3 kernel-boundary launch/drain gaps; fused kernel also becomes
// visible in rocprof top-5 (diagnostic).
// ---------------------------------------------------------------------------
__global__ __launch_bounds__(256, 2) void fused_pipeline(
    const float* __restrict__ x,  const float* __restrict__ rc,
    const float* __restrict__ rs,
    const float* __restrict__ Wq, const float* __restrict__ Wk,
    const float* __restrict__ Wv, const float* __restrict__ Wo,
    float* __restrict__ out, ushort_t* __restrict__ ws)
{
    __shared__ __align__(16) char smem[65536];
    cg::grid_group grid = cg::this_grid();

    ushort_t* xb    = ws;                                  // 2048*1024
    ushort_t* WqT   = xb  + (size_t)2048 * 1024;           // 1024*1024
    ushort_t* WkT   = WqT + (size_t)1024 * 1024;           //  256*1024
    ushort_t* WvT   = WkT + (size_t)256 * 1024;            //  256*1024
    ushort_t* WoT   = WvT + (size_t)256 * 1024;            // 1024*1024
    ushort_t* Qb    = WoT + (size_t)1024 * 1024;           // 16*2048*64
    ushort_t* Kb    = Qb  + (size_t)NH * S_LEN * HD;       //  4*2048*64
    ushort_t* Vtb   = Kb  + (size_t)NKV * S_LEN * HD;      //  4*64*2048
    ushort_t* attnb = Vtb + (size_t)NKV * HD * S_LEN;      // 2048*1024

    const int bid = blockIdx.x;
    const int t = threadIdx.x;
    const int lane = t & 63, wave = t >> 6;
    const int quad = lane >> 4, l15 = lane & 15;
    const int lq = lane >> 3, lr = lane & 7;
    const int swz_st = (lr ^ lq) * 8;
    const int l7 = l15 & 7;
    const int fsw0 = (quad ^ l7) * 8;
    const int fsw1 = ((quad + 4) ^ l7) * 8;

    // ------------------------- phase 0: prep -------------------------
    for (int unit = bid; unit < 896; unit += 512) {
        if (unit < 256) {
            // x fp32 -> bf16, 256 units x 8 reps x 1024 elems
            const int i0 = (unit * 256 + t) * 4;
            #pragma unroll
            for (int rep = 0; rep < 8; ++rep) {
                const int i = i0 + rep * 262144;
                float4 v = *(const float4*)(x + i);
                ushort4v o = { f2bf(v.x), f2bf(v.y), f2bf(v.z), f2bf(v.w) };
                *(ushort4v*)(xb + i) = o;
            }
        } else {
            // weight transpose+cast, 640 units
            ushort_t* T = (ushort_t*)smem;     // 64*72
            const int tu = unit - 256;
            const float* W; ushort_t* WT; int N, kx, ny;
            if (tu < 256)      { W = Wq; WT = WqT; N = 1024; kx = tu & 15;         ny = tu >> 4; }
            else if (tu < 320) { W = Wk; WT = WkT; N = 256;  kx = (tu - 256) & 15; ny = (tu - 256) >> 4; }
            else if (tu < 384) { W = Wv; WT = WvT; N = 256;  kx = (tu - 320) & 15; ny = (tu - 320) >> 4; }
            else               { W = Wo; WT = WoT; N = 1024; kx = (tu - 384) & 15; ny = (tu - 384) >> 4; }
            const int n0 = ny * 64, k0 = kx * 64;
            const int kr = t >> 4, nc = (t & 15) * 4;
            __syncthreads();                   // WAR guard vs previous unit
            #pragma unroll
            for (int p = 0; p < 4; ++p) {
                const int k = kr + p * 16;
                float4 v = *(const float4*)(W + (size_t)(k0 + k) * N + n0 + nc);
                T[(nc + 0) * 72 + k] = f2bf(v.x);
                T[(nc + 1) * 72 + k] = f2bf(v.y);
                T[(nc + 2) * 72 + k] = f2bf(v.z);
                T[(nc + 3) * 72 + k] = f2bf(v.w);
            }
            __syncthreads();
            const int n = t >> 2, seg = (t & 3) * 16;
            ushort8v a = *(ushort8v*)&T[n * 72 + seg];
            ushort8v b = *(ushort8v*)&T[n * 72 + seg + 8];
            *(ushort8v*)(WT + (size_t)(n0 + n) * 1024 + k0 + seg)     = a;
            *(ushort8v*)(WT + (size_t)(n0 + n) * 1024 + k0 + seg + 8) = b;
        }
    }
    grid.sync();

    // ------------------------- phase 1: QKV gemm + RoPE ---------------
    if (bid < 384) {
        ushort_t* As = (ushort_t*)smem;               // [2][64*64]
        ushort_t* Bs = (ushort_t*)(smem + 16384);     // [2][128*64]
        const int wr = wave >> 1, wc = wave & 1;
        const int m0 = (bid & 31) * 64;
        const int cy = bid >> 5;

        const ushort_t* WT; int nloc;
        if (cy < 8)       { WT = WqT; nloc = cy * 128; }
        else if (cy < 10) { WT = WkT; nloc = (cy - 8) * 128; }
        else              { WT = WvT; nloc = (cy - 10) * 128; }

        f32x4 acc[2][4];
        #pragma unroll
        for (int i = 0; i < 2; ++i)
            #pragma unroll
            for (int j = 0; j < 4; ++j) acc[i][j] = (f32x4)0.f;

        auto stage = [&](int buf, int k0) {
            #pragma unroll
            for (int i = 0; i < 2; ++i) {
                const int r = wave * 16 + i * 8 + lq;
                cp16(&As[buf * 4096 + (wave * 16 + i * 8) * 64],
                     xb + (size_t)(m0 + r) * 1024 + k0 + swz_st);
            }
            #pragma unroll
            for (int i = 0; i < 4; ++i) {
                const int r = wave * 32 + i * 8 + lq;
                cp16(&Bs[buf * 8192 + (wave * 32 + i * 8) * 64],
                     WT + (size_t)(nloc + r) * 1024 + k0 + swz_st);
            }
        };

        stage(0, 0);
        __syncthreads();

        for (int kk = 0; kk < 16; ++kk) {
            const int cur = kk & 1;
            if (kk + 1 < 16) stage(cur ^ 1, (kk + 1) * 64);

            const ushort_t* Ac = &As[cur * 4096];
            const ushort_t* Bc = &Bs[cur * 8192];
            #pragma unroll
            for (int h = 0; h < 2; ++h) {
                const int fsw = h ? fsw1 : fsw0;
                short8 av[2], bv[4];
                #pragma unroll
                for (int i = 0; i < 2; ++i)
                    av[i] = *(const short8*)&Ac[(wr * 32 + i * 16 + l15) * 64 + fsw];
                #pragma unroll
                for (int j = 0; j < 4; ++j)
                    bv[j] = *(const short8*)&Bc[(wc * 64 + j * 16 + l15) * 64 + fsw];
                #pragma unroll
                for (int i = 0; i < 2; ++i)
                    #pragma unroll
                    for (int j = 0; j < 4; ++j)
                        acc[i][j] = __builtin_amdgcn_mfma_f32_16x16x32_bf16(
                            av[i], bv[j], acc[i][j], 0, 0, 0);
            }
            __syncthreads();
        }

        // epilogue: C/D layout col = l15 (+16j), row = quad*4+reg (+16i)  [m89]
        if (cy < 10) {
            ushort_t* dst = (cy < 8) ? Qb : Kb;
            const int h = ((cy < 8) ? cy : (cy - 8)) * 2 + wc;
            #pragma unroll
            for (int i = 0; i < 2; ++i) {
                #pragma unroll
                for (int j = 0; j < 2; ++j) {
                    const int d = j * 16 + l15;
                    #pragma unroll
                    for (int reg = 0; reg < 4; ++reg) {
                        const int s = m0 + wr * 32 + i * 16 + quad * 4 + reg;
                        const float c  = rc[s * 32 + d];
                        const float sn = rs[s * 32 + d];
                        const float v1 = acc[i][j][reg];
                        const float v2 = acc[i][j + 2][reg];
                        dst[((size_t)h * S_LEN + s) * HD + d]      = f2bf(v1 * c - v2 * sn);
                        dst[((size_t)h * S_LEN + s) * HD + d + 32] = f2bf(v2 * c + v1 * sn);
                    }
                }
            }
        } else {
            const int vh = (cy - 10) * 2 + wc;
            #pragma unroll
            for (int i = 0; i < 2; ++i) {
                const int s0 = m0 + wr * 32 + i * 16 + quad * 4;
                #pragma unroll
                for (int j = 0; j < 4; ++j) {
                    const int d = j * 16 + l15;
                    ushort4v o = { f2bf(acc[i][j][0]), f2bf(acc[i][j][1]),
                                   f2bf(acc[i][j][2]), f2bf(acc[i][j][3]) };
                    *(ushort4v*)&Vtb[((size_t)vh * HD + d) * S_LEN + s0] = o;
                }
            }
        }
    }
    grid.sync();

    // ------------------------- phase 2: flash attention ----------------
    {
        ushort_t* Ks = (ushort_t*)smem;               // [2][2][64*64]
        ushort_t* Vs = (ushort_t*)(smem + 32768);     // [2][2][64*64]

        // V-frag b64 offsets (ushort units) for pi-ordered K slots
        const int vq  = quad >> 1;
        const int q14 = (quad & 1) << 2;
        const int vo0 = (((0 + vq) ^ l7) << 3) + q14;
        const int vo1 = (((2 + vq) ^ l7) << 3) + q14;
        const int vo2 = (((4 + vq) ^ l7) << 3) + q14;
        const int vo3 = (((6 + vq) ^ l7) << 3) + q14;

        const int h  = bid & 15;
        const int y  = bid >> 4;
        const int qt = (y < 16) ? y : 47 - y;
        const int q0 = qt * 64;
        const int kvh = h >> 2;
        const int qrow0 = q0 + wave * 16;

        const ushort_t* Qg = Qb + ((size_t)h * S_LEN + qrow0) * HD;
        const ushort_t* Kg = Kb + (size_t)kvh * S_LEN * HD;
        const ushort_t* Vg = Vtb + (size_t)kvh * HD * S_LEN;

        short8 aq0 = *(const short8*)(Qg + (size_t)l15 * HD + quad * 8);
        short8 aq1 = *(const short8*)(Qg + (size_t)l15 * HD + 32 + quad * 8);

        float psum = 0.f;
        f32x4 Oacc[4];
        #pragma unroll
        for (int jb = 0; jb < 4; ++jb) Oacc[jb] = (f32x4)0.f;

        const int nround = (qt + 2) >> 1;

        auto stage = [&](int buf, int kvbase) {
            #pragma unroll
            for (int u = 0; u < 2; ++u)
                #pragma unroll
                for (int i = 0; i < 2; ++i) {
                    const int r = wave * 16 + i * 8 + lq;
                    cp16(&Ks[(buf * 2 + u) * 4096 + (wave * 16 + i * 8) * 64],
                         Kg + (size_t)(kvbase + u * 64 + r) * 64 + swz_st);
                    cp16(&Vs[(buf * 2 + u) * 4096 + (wave * 16 + i * 8) * 64],
                         Vg + (size_t)r * 2048 + kvbase + u * 64 + swz_st);
                }
        };

        stage(0, 0);
        __syncthreads();

        for (int round = 0; round < nround; ++round) {
            const int cur = round & 1;
            if (round + 1 < nround) stage(cur ^ 1, (round + 1) * 128);

            #pragma unroll
            for (int u = 0; u < 2; ++u) {
                const int kv0 = round * 128 + u * 64;
                if (kv0 > q0 + 63) break;        // fully masked sub-tile
                const ushort_t* Kc = &Ks[(cur * 2 + u) * 4096];
                const ushort_t* Vc = &Vs[(cur * 2 + u) * 4096];

                // S^T = K Q (swapped operands)
                f32x4 sv[4];
                #pragma unroll
                for (int jb = 0; jb < 4; ++jb) {
                    short8 k0 = *(const short8*)&Kc[(jb * 16 + l15) * 64 + fsw0];
                    short8 k1 = *(const short8*)&Kc[(jb * 16 + l15) * 64 + fsw1];
                    f32x4 z = (f32x4)0.f;
                    z = __builtin_amdgcn_mfma_f32_16x16x32_bf16(k0, aq0, z, 0, 0, 0);
                    z = __builtin_amdgcn_mfma_f32_16x16x32_bf16(k1, aq1, z, 0, 0, 0);
                    sv[jb] = z;
                }

                // max-free softmax: P = exp(s/8); mask only on diagonal sub-tile
                const bool diag = (kv0 == q0);
                const int qg = qrow0 + l15;
                #pragma unroll
                for (int jb = 0; jb < 4; ++jb) {
                    #pragma unroll
                    for (int reg = 0; reg < 4; ++reg) {
                        float e = __expf(sv[jb][reg] * 0.125f);
                        if (diag && (kv0 + jb * 16 + quad * 4 + reg) > qg) e = 0.f;
                        sv[jb][reg] = e;
                        psum += e;
                    }
                }

                // P A-frags from the lane's own registers (pi ordering)
                short8 p0 = { (short)f2bf(sv[0][0]), (short)f2bf(sv[0][1]),
                              (short)f2bf(sv[0][2]), (short)f2bf(sv[0][3]),
                              (short)f2bf(sv[1][0]), (short)f2bf(sv[1][1]),
                              (short)f2bf(sv[1][2]), (short)f2bf(sv[1][3]) };
                short8 p1 = { (short)f2bf(sv[2][0]), (short)f2bf(sv[2][1]),
                              (short)f2bf(sv[2][2]), (short)f2bf(sv[2][3]),
                              (short)f2bf(sv[3][0]), (short)f2bf(sv[3][1]),
                              (short)f2bf(sv[3][2]), (short)f2bf(sv[3][3]) };

                // O += P V with pi-ordered V gather
                #pragma unroll
                for (int jb = 0; jb < 4; ++jb) {
                    const ushort_t* Vrow = &Vc[(jb * 16 + l15) * 64];
                    short4v va0 = *(const short4v*)&Vrow[vo0];
                    short4v va1 = *(const short4v*)&Vrow[vo1];
                    short4v va2 = *(const short4v*)&Vrow[vo2];
                    short4v va3 = *(const short4v*)&Vrow[vo3];
                    short8 v0 = __builtin_shufflevector(va0, va1, 0, 1, 2, 3, 4, 5, 6, 7);
                    short8 v1 = __builtin_shufflevector(va2, va3, 0, 1, 2, 3, 4, 5, 6, 7);
                    Oacc[jb] = __builtin_amdgcn_mfma_f32_16x16x32_bf16(p0, v0, Oacc[jb], 0, 0, 0);
                    Oacc[jb] = __builtin_amdgcn_mfma_f32_16x16x32_bf16(p1, v1, Oacc[jb], 0, 0, 0);
                }
            }

            __syncthreads();
        }

        psum += __shfl_xor(psum, 16);
        psum += __shfl_xor(psum, 32);
        #pragma unroll
        for (int reg = 0; reg < 4; ++reg) {
            const float inv = 1.f / __shfl(psum, quad * 4 + reg);
            const int s = qrow0 + quad * 4 + reg;
            #pragma unroll
            for (int jb = 0; jb < 4; ++jb)
                attnb[(size_t)s * D_MODEL + h * HD + jb * 16 + l15] =
                    f2bf(Oacc[jb][reg] * inv);
        }
    }
    grid.sync();

    // ------------------------- phase 3: output projection ---------------
    {
        ushort_t* As = (ushort_t*)smem;               // [2][64*64]
        ushort_t* Bs = (ushort_t*)(smem + 16384);     // [2][64*64]
        const int wr = wave >> 1, wc = wave & 1;
        const int m0 = (bid & 31) * 64;
        const int n0 = (bid >> 5) * 64;

        f32x4 acc[2][2];
        #pragma unroll
        for (int i = 0; i < 2; ++i)
            #pragma unroll
            for (int j = 0; j < 2; ++j) acc[i][j] = (f32x4)0.f;

        auto stage = [&](int buf, int k0) {
            #pragma unroll
            for (int i = 0; i < 2; ++i) {
                const int r = wave * 16 + i * 8 + lq;
                cp16(&As[buf * 4096 + (wave * 16 + i * 8) * 64],
                     attnb + (size_t)(m0 + r) * 1024 + k0 + swz_st);
                cp16(&Bs[buf * 4096 + (wave * 16 + i * 8) * 64],
                     WoT + (size_t)(n0 + r) * 1024 + k0 + swz_st);
            }
        };

        stage(0, 0);
        __syncthreads();

        for (int kk = 0; kk < 16; ++kk) {
            const int cur = kk & 1;
            if (kk + 1 < 16) stage(cur ^ 1, (kk + 1) * 64);

            const ushort_t* Ac = &As[cur * 4096];
            const ushort_t* Bc = &Bs[cur * 4096];
            #pragma unroll
            for (int h = 0; h < 2; ++h) {
                const int fsw = h ? fsw1 : fsw0;
                short8 av[2], bv[2];
                #pragma unroll
                for (int i = 0; i < 2; ++i)
                    av[i] = *(const short8*)&Ac[(wr * 32 + i * 16 + l15) * 64 + fsw];
                #pragma unroll
                for (int j = 0; j < 2; ++j)
                    bv[j] = *(const short8*)&Bc[(wc * 32 + j * 16 + l15) * 64 + fsw];
                #pragma unroll
                for (int i = 0; i < 2; ++i)
                    #pragma unroll
                    for (int j = 0; j < 2; ++j)
                        acc[i][j] = __builtin_amdgcn_mfma_f32_16x16x32_bf16(
                            av[i], bv[j], acc[i][j], 0, 0, 0);
            }
            __syncthreads();
        }

        #pragma unroll
        for (int i = 0; i < 2; ++i)
            #pragma unroll
            for (int reg = 0; reg < 4; ++reg) {
                const int s = m0 + wr * 32 + i * 16 + quad * 4 + reg;
                #pragma unroll
                for (int j = 0; j < 2; ++j)
                    out[(size_t)s * D_MODEL + n0 + wc * 32 + j * 16 + l15] =
                        acc[i][j][reg];
            }
    }
}

// ---------------------------------------------------------------------------
extern "C" void kernel_launch(void* const* d_in, const int* in_sizes, int n_in,
                              void* d_out, int out_size, void* d_ws, size_t ws_size,
                              hipStream_t stream)
{
    const float* x  = (const float*)d_in[0];
    const float* rc = (const float*)d_in[1];
    const float* rs = (const float*)d_in[2];
    const float* Wq = (const float*)d_in[3];
    const float* Wk = (const float*)d_in[4];
    const float* Wv = (const float*)d_in[5];
    const float* Wo = (const float*)d_in[6];
    float* out = (float*)d_out;
    ushort_t* ws = (ushort_t*)d_ws;

    void* args[] = { (void*)&x, (void*)&rc, (void*)&rs, (void*)&Wq,
                     (void*)&Wk, (void*)&Wv, (void*)&Wo, (void*)&out,
                     (void*)&ws };
    hipLaunchCooperativeKernel((void*)fused_pipeline, dim3(512), dim3(256),
                               args, 0, stream);
}

// Round 5
// 142.843 us; speedup vs baseline: 2.3378x; 2.3378x over previous
//
#include <hip/hip_runtime.h>

typedef unsigned short ushort_t;
typedef __attribute__((ext_vector_type(8))) short short8;
typedef __attribute__((ext_vector_type(4))) float f32x4;
typedef __attribute__((ext_vector_type(4))) unsigned short ushort4v;
typedef __attribute__((ext_vector_type(8))) unsigned short ushort8v;

#define S_LEN 2048
#define D_MODEL 1024
#define NH 16
#define NKV 4
#define HD 64

// fp32 -> bf16 round-to-nearest-even
__device__ __forceinline__ ushort_t f2bf(float f) {
    unsigned u = __float_as_uint(f);
    u += 0x7fffu + ((u >> 16) & 1u);
    return (ushort_t)(u >> 16);
}

// async global->LDS, 16B/lane; LDS base wave-uniform, HW scatters lane*16
__device__ __forceinline__ void cp16(void* lds, const void* g) {
    __builtin_amdgcn_global_load_lds(
        (__attribute__((address_space(1))) void*)g,
        (__attribute__((address_space(3))) void*)lds, 16, 0, 0);
}

// ---------------------------------------------------------------------------
// Preprocess: z=0..3 -> weight transpose+cast W[k][n] fp32 -> WT[n][k] bf16;
// z=4 -> x fp32 -> bf16. grid (16,16,5).  (baseline verbatim)
// ---------------------------------------------------------------------------
__global__ __launch_bounds__(256) void prep_kernel(
    const float* __restrict__ x, ushort_t* __restrict__ xb,
    const float* __restrict__ Wq, const float* __restrict__ Wk,
    const float* __restrict__ Wv, const float* __restrict__ Wo,
    ushort_t* __restrict__ WqT, ushort_t* __restrict__ WkT,
    ushort_t* __restrict__ WvT, ushort_t* __restrict__ WoT)
{
    const int t = threadIdx.x;
    if (blockIdx.z == 4) {
        const int b  = blockIdx.y * 16 + blockIdx.x;
        const int i0 = (b * 256 + t) * 4;
        #pragma unroll
        for (int rep = 0; rep < 8; ++rep) {
            const int i = i0 + rep * 262144;   // 8 x 256K covers 2048*1024
            float4 v = *(const float4*)(x + i);
            ushort4v o = { f2bf(v.x), f2bf(v.y), f2bf(v.z), f2bf(v.w) };
            *(ushort4v*)(xb + i) = o;
        }
        return;
    }
    __shared__ ushort_t T[64 * 72];
    const float* W; ushort_t* WT; int N;
    switch (blockIdx.z) {
        case 0:  W = Wq; WT = WqT; N = 1024; break;
        case 1:  W = Wk; WT = WkT; N = 256;  break;
        case 2:  W = Wv; WT = WvT; N = 256;  break;
        default: W = Wo; WT = WoT; N = 1024; break;
    }
    const int n0 = blockIdx.y * 64;
    if (n0 >= N) return;
    const int k0 = blockIdx.x * 64;
    const int kr = t >> 4, nc = (t & 15) * 4;
    #pragma unroll
    for (int p = 0; p < 4; ++p) {
        const int k = kr + p * 16;
        float4 v = *(const float4*)(W + (size_t)(k0 + k) * N + n0 + nc);
        T[(nc + 0) * 72 + k] = f2bf(v.x);
        T[(nc + 1) * 72 + k] = f2bf(v.y);
        T[(nc + 2) * 72 + k] = f2bf(v.z);
        T[(nc + 3) * 72 + k] = f2bf(v.w);
    }
    __syncthreads();
    const int n = t >> 2, seg = (t & 3) * 16;
    ushort8v a = *(ushort8v*)&T[n * 72 + seg];
    ushort8v b = *(ushort8v*)&T[n * 72 + seg + 8];
    *(ushort8v*)(WT + (size_t)(n0 + n) * 1024 + k0 + seg)     = a;
    *(ushort8v*)(WT + (size_t)(n0 + n) * 1024 + k0 + seg + 8) = b;
}

// ---------------------------------------------------------------------------
// QKV projection, ROUND 5: 64(M)x64(N) tile, BK=64, dbuf swizzled LDS (32 KB).
// grid (32, 24) = 768 blocks = EXACTLY 3 balanced rounds on 256 CUs (was 384
// = 1.5 rounds, half the machine idle in round 2), and 32 KB LDS allows up to
// 5 co-resident blocks/CU to overlap the per-k-step barrier drains.
// cy 0..15 -> Q head cy; 16..19 -> K head cy-16; 20..23 -> V head cy-20.
// N-tile == one head. RoPE pair (d, d+32) kept in-wave: each wave's two
// N-frags are interleaved cols {wc*16, wc*16+32}.
// ---------------------------------------------------------------------------
__global__ __launch_bounds__(256, 2) void gemm_qkv_mfma(
    const ushort_t* __restrict__ xb, const ushort_t* __restrict__ WqT,
    const ushort_t* __restrict__ WkT, const ushort_t* __restrict__ WvT,
    const float* __restrict__ rc, const float* __restrict__ rs,
    ushort_t* __restrict__ Qb, ushort_t* __restrict__ Kb,
    ushort_t* __restrict__ Vtb)
{
    __shared__ ushort_t As[2][64 * 64];    // 16 KB
    __shared__ ushort_t Bs[2][64 * 64];    // 16 KB

    const int t = threadIdx.x;
    const int lane = t & 63, wave = t >> 6;
    const int wr = wave >> 1, wc = wave & 1;
    const int quad = lane >> 4, l15 = lane & 15;
    const int lq = lane >> 3, lr = lane & 7;
    const int swz_st = (lr ^ lq) * 8;
    const int l7 = l15 & 7;
    const int fsw0 = (quad ^ l7) * 8;
    const int fsw1 = ((quad + 4) ^ l7) * 8;

    const int m0 = blockIdx.x * 64;
    const int cy = blockIdx.y;

    const ushort_t* WT; int nloc;
    if (cy < 16)      { WT = WqT; nloc = cy * 64; }
    else if (cy < 20) { WT = WkT; nloc = (cy - 16) * 64; }
    else              { WT = WvT; nloc = (cy - 20) * 64; }

    f32x4 acc[2][2];
    #pragma unroll
    for (int i = 0; i < 2; ++i)
        #pragma unroll
        for (int j = 0; j < 2; ++j) acc[i][j] = (f32x4)0.f;

    auto stage = [&](int buf, int k0) {
        #pragma unroll
        for (int i = 0; i < 2; ++i) {
            const int r = wave * 16 + i * 8 + lq;
            cp16(&As[buf][(wave * 16 + i * 8) * 64],
                 xb + (size_t)(m0 + r) * 1024 + k0 + swz_st);
            cp16(&Bs[buf][(wave * 16 + i * 8) * 64],
                 WT + (size_t)(nloc + r) * 1024 + k0 + swz_st);
        }
    };

    stage(0, 0);
    __syncthreads();

    for (int kk = 0; kk < 16; ++kk) {
        const int cur = kk & 1;
        if (kk + 1 < 16) stage(cur ^ 1, (kk + 1) * 64);

        const ushort_t* Ac = &As[cur][0];
        const ushort_t* Bc = &Bs[cur][0];
        #pragma unroll
        for (int h = 0; h < 2; ++h) {
            const int fsw = h ? fsw1 : fsw0;
            short8 av[2], bv[2];
            #pragma unroll
            for (int i = 0; i < 2; ++i)
                av[i] = *(const short8*)&Ac[(wr * 32 + i * 16 + l15) * 64 + fsw];
            #pragma unroll
            for (int j = 0; j < 2; ++j)   // interleaved cols wc*16 + j*32
                bv[j] = *(const short8*)&Bc[(wc * 16 + j * 32 + l15) * 64 + fsw];
            #pragma unroll
            for (int i = 0; i < 2; ++i)
                #pragma unroll
                for (int j = 0; j < 2; ++j)
                    acc[i][j] = __builtin_amdgcn_mfma_f32_16x16x32_bf16(
                        av[i], bv[j], acc[i][j], 0, 0, 0);
        }
        __syncthreads();
    }

    // epilogue: C/D layout col = l15, row = quad*4+reg (+16i)  [m89]
    // acc[i][0] -> head-local col d = wc*16+l15 (0..31); acc[i][1] -> d+32.
    if (cy < 20) {
        ushort_t* dst = (cy < 16) ? Qb : Kb;
        const int h = (cy < 16) ? cy : (cy - 16);
        const int d = wc * 16 + l15;
        #pragma unroll
        for (int i = 0; i < 2; ++i) {
            #pragma unroll
            for (int reg = 0; reg < 4; ++reg) {
                const int s = m0 + wr * 32 + i * 16 + quad * 4 + reg;
                const float c  = rc[s * 32 + d];
                const float sn = rs[s * 32 + d];
                const float v1 = acc[i][0][reg];    // x[d]
                const float v2 = acc[i][1][reg];    // x[d+32]
                dst[((size_t)h * S_LEN + s) * HD + d]      = f2bf(v1 * c - v2 * sn);
                dst[((size_t)h * S_LEN + s) * HD + d + 32] = f2bf(v2 * c + v1 * sn);
            }
        }
    } else {
        const int vh = cy - 20;
        #pragma unroll
        for (int i = 0; i < 2; ++i) {
            const int s0 = m0 + wr * 32 + i * 16 + quad * 4;
            #pragma unroll
            for (int j = 0; j < 2; ++j) {
                const int d = wc * 16 + j * 32 + l15;
                ushort4v o = { f2bf(acc[i][j][0]), f2bf(acc[i][j][1]),
                               f2bf(acc[i][j][2]), f2bf(acc[i][j][3]) };
                *(ushort4v*)&Vtb[((size_t)vh * HD + d) * S_LEN + s0] = o;
            }
        }
    }
}

// ---------------------------------------------------------------------------
// MFMA flash attention. grid (NH, 32), snake q-tile map (CU pairs ~17 rounds).
// BKV=128 per barrier round. Max-free softmax; one final shuffle-reduce.
// (144.23 baseline verbatim)
// ---------------------------------------------------------------------------
__global__ __launch_bounds__(256, 2) void attn_mfma(
    const ushort_t* __restrict__ Qb, const ushort_t* __restrict__ Kb,
    const ushort_t* __restrict__ Vtb, ushort_t* __restrict__ attnb)
{
    __shared__ ushort_t Ks[2][2][64 * 64];   // 32 KB [buf][sub][kv][d] swizzled
    __shared__ ushort_t Vs[2][2][64 * 64];   // 32 KB [buf][sub][d][kv] swizzled
    __shared__ ushort_t Ps[4][16 * 72];      // 9 KB wave-private P

    const int t = threadIdx.x;
    const int lane = t & 63, wave = t >> 6;
    const int quad = lane >> 4, l15 = lane & 15;
    const int lq = lane >> 3, lr = lane & 7;
    const int swz_st = (lr ^ lq) * 8;
    const int l7 = l15 & 7;
    const int fsw0 = (quad ^ l7) * 8;
    const int fsw1 = ((quad + 4) ^ l7) * 8;

    const int h  = blockIdx.x;
    const int y  = blockIdx.y;
    const int qt = (y < 16) ? y : 47 - y;
    const int q0 = qt * 64;
    const int kvh = h >> 2;
    const int qrow0 = q0 + wave * 16;

    const ushort_t* Qg = Qb + ((size_t)h * S_LEN + qrow0) * HD;
    const ushort_t* Kg = Kb + (size_t)kvh * S_LEN * HD;
    const ushort_t* Vg = Vtb + (size_t)kvh * HD * S_LEN;

    short8 aq0 = *(const short8*)(Qg + (size_t)l15 * HD + quad * 8);
    short8 aq1 = *(const short8*)(Qg + (size_t)l15 * HD + 32 + quad * 8);

    float ps4[4] = {0.f, 0.f, 0.f, 0.f};
    f32x4 Oacc[4];
    #pragma unroll
    for (int jb = 0; jb < 4; ++jb) Oacc[jb] = (f32x4)0.f;

    const int nround = (qt + 2) >> 1;   // rounds of 128 KV cols

    auto stage = [&](int buf, int kvbase) {
        #pragma unroll
        for (int u = 0; u < 2; ++u)
            #pragma unroll
            for (int i = 0; i < 2; ++i) {
                const int r = wave * 16 + i * 8 + lq;
                cp16(&Ks[buf][u][(wave * 16 + i * 8) * 64],
                     Kg + (size_t)(kvbase + u * 64 + r) * 64 + swz_st);
                cp16(&Vs[buf][u][(wave * 16 + i * 8) * 64],
                     Vg + (size_t)r * 2048 + kvbase + u * 64 + swz_st);
            }
    };

    stage(0, 0);
    __syncthreads();

    ushort_t* Pw = &Ps[wave][0];

    for (int round = 0; round < nround; ++round) {
        const int cur = round & 1;
        if (round + 1 < nround) stage(cur ^ 1, (round + 1) * 128);

        #pragma unroll
        for (int u = 0; u < 2; ++u) {
            const int kv0 = round * 128 + u * 64;
            if (kv0 > q0 + 63) break;        // fully masked sub-tile
            const ushort_t* Kc = &Ks[cur][u][0];
            const ushort_t* Vc = &Vs[cur][u][0];

            // S = Q K^T
            f32x4 sv[4];
            #pragma unroll
            for (int jb = 0; jb < 4; ++jb) {
                short8 b0 = *(const short8*)&Kc[(jb * 16 + l15) * 64 + fsw0];
                short8 b1 = *(const short8*)&Kc[(jb * 16 + l15) * 64 + fsw1];
                f32x4 z = (f32x4)0.f;
                z = __builtin_amdgcn_mfma_f32_16x16x32_bf16(aq0, b0, z, 0, 0, 0);
                z = __builtin_amdgcn_mfma_f32_16x16x32_bf16(aq1, b1, z, 0, 0, 0);
                sv[jb] = z;
            }

            // max-free softmax: P = exp(s/8); mask only on the diagonal sub-tile
            const bool diag = (kv0 == q0);
            #pragma unroll
            for (int jb = 0; jb < 4; ++jb) {
                const int col = kv0 + jb * 16 + l15;
                #pragma unroll
                for (int reg = 0; reg < 4; ++reg) {
                    float e = __expf(sv[jb][reg] * 0.125f);
                    if (diag && col > qrow0 + quad * 4 + reg) e = 0.f;
                    sv[jb][reg] = e;
                    ps4[reg] += e;
                }
            }

            // P: C-layout -> wave-private LDS -> A-layout frags  [m120]
            #pragma unroll
            for (int jb = 0; jb < 4; ++jb)
                #pragma unroll
                for (int reg = 0; reg < 4; ++reg)
                    Pw[(quad * 4 + reg) * 72 + jb * 16 + l15] = f2bf(sv[jb][reg]);
            short8 p0 = *(const short8*)&Pw[l15 * 72 + quad * 8];
            short8 p1 = *(const short8*)&Pw[l15 * 72 + 32 + quad * 8];

            // O += P V
            #pragma unroll
            for (int jb = 0; jb < 4; ++jb) {
                short8 v0 = *(const short8*)&Vc[(jb * 16 + l15) * 64 + fsw0];
                short8 v1 = *(const short8*)&Vc[(jb * 16 + l15) * 64 + fsw1];
                Oacc[jb] = __builtin_amdgcn_mfma_f32_16x16x32_bf16(p0, v0, Oacc[jb], 0, 0, 0);
                Oacc[jb] = __builtin_amdgcn_mfma_f32_16x16x32_bf16(p1, v1, Oacc[jb], 0, 0, 0);
            }
        }

        __syncthreads();   // drain stage(round+1), guard buffer reuse
    }

    // final row-sum reduction + normalize + store
    #pragma unroll
    for (int reg = 0; reg < 4; ++reg) {
        float l = ps4[reg];
        l += __shfl_xor(l, 1);
        l += __shfl_xor(l, 2);
        l += __shfl_xor(l, 4);
        l += __shfl_xor(l, 8);
        const float inv = 1.f / l;
        const int s = qrow0 + quad * 4 + reg;
        #pragma unroll
        for (int jb = 0; jb < 4; ++jb)
            attnb[(size_t)s * D_MODEL + h * HD + jb * 16 + l15] =
                f2bf(Oacc[jb][reg] * inv);
    }
}

// ---------------------------------------------------------------------------
// Output projection. 64x64 tile, BK=64, swizzled dbuf LDS.
// grid (32, 16) = 512 blocks.  (144.23 baseline verbatim)
// ---------------------------------------------------------------------------
__global__ __launch_bounds__(256, 4) void gemm_out_mfma(
    const ushort_t* __restrict__ Ab, const ushort_t* __restrict__ WoT,
    float* __restrict__ out)
{
    __shared__ ushort_t As[2][64 * 64];
    __shared__ ushort_t Bs[2][64 * 64];

    const int t = threadIdx.x;
    const int lane = t & 63, wave = t >> 6;
    const int wr = wave >> 1, wc = wave & 1;
    const int quad = lane >> 4, l15 = lane & 15;
    const int lq = lane >> 3, lr = lane & 7;
    const int swz_st = (lr ^ lq) * 8;
    const int l7 = l15 & 7;
    const int fsw0 = (quad ^ l7) * 8;
    const int fsw1 = ((quad + 4) ^ l7) * 8;

    const int m0 = blockIdx.x * 64;
    const int n0 = blockIdx.y * 64;

    f32x4 acc[2][2];
    #pragma unroll
    for (int i = 0; i < 2; ++i)
        #pragma unroll
        for (int j = 0; j < 2; ++j) acc[i][j] = (f32x4)0.f;

    auto stage = [&](int buf, int k0) {
        #pragma unroll
        for (int i = 0; i < 2; ++i) {
            const int r = wave * 16 + i * 8 + lq;
            cp16(&As[buf][(wave * 16 + i * 8) * 64],
                 Ab + (size_t)(m0 + r) * 1024 + k0 + swz_st);
            cp16(&Bs[buf][(wave * 16 + i * 8) * 64],
                 WoT + (size_t)(n0 + r) * 1024 + k0 + swz_st);
        }
    };

    stage(0, 0);
    __syncthreads();

    for (int kk = 0; kk < 16; ++kk) {
        const int cur = kk & 1;
        if (kk + 1 < 16) stage(cur ^ 1, (kk + 1) * 64);

        const ushort_t* Ac = &As[cur][0];
        const ushort_t* Bc = &Bs[cur][0];
        #pragma unroll
        for (int h = 0; h < 2; ++h) {
            const int fsw = h ? fsw1 : fsw0;
            short8 av[2], bv[2];
            #pragma unroll
            for (int i = 0; i < 2; ++i)
                av[i] = *(const short8*)&Ac[(wr * 32 + i * 16 + l15) * 64 + fsw];
            #pragma unroll
            for (int j = 0; j < 2; ++j)
                bv[j] = *(const short8*)&Bc[(wc * 32 + j * 16 + l15) * 64 + fsw];
            #pragma unroll
            for (int i = 0; i < 2; ++i)
                #pragma unroll
                for (int j = 0; j < 2; ++j)
                    acc[i][j] = __builtin_amdgcn_mfma_f32_16x16x32_bf16(
                        av[i], bv[j], acc[i][j], 0, 0, 0);
        }
        __syncthreads();
    }

    #pragma unroll
    for (int i = 0; i < 2; ++i)
        #pragma unroll
        for (int reg = 0; reg < 4; ++reg) {
            const int s = m0 + wr * 32 + i * 16 + quad * 4 + reg;
            #pragma unroll
            for (int j = 0; j < 2; ++j)
                out[(size_t)s * D_MODEL + n0 + wc * 32 + j * 16 + l15] = acc[i][j][reg];
        }
}

// ---------------------------------------------------------------------------
extern "C" void kernel_launch(void* const* d_in, const int* in_sizes, int n_in,
                              void* d_out, int out_size, void* d_ws, size_t ws_size,
                              hipStream_t stream)
{
    const float* x  = (const float*)d_in[0];
    const float* rc = (const float*)d_in[1];
    const float* rs = (const float*)d_in[2];
    const float* Wq = (const float*)d_in[3];
    const float* Wk = (const float*)d_in[4];
    const float* Wv = (const float*)d_in[5];
    const float* Wo = (const float*)d_in[6];
    float* out = (float*)d_out;

    ushort_t* xb   = (ushort_t*)d_ws;                          // 2048*1024
    ushort_t* WqT  = xb   + (size_t)2048 * 1024;               // 1024*1024
    ushort_t* WkT  = WqT  + (size_t)1024 * 1024;               //  256*1024
    ushort_t* WvT  = WkT  + (size_t)256 * 1024;                //  256*1024
    ushort_t* WoT  = WvT  + (size_t)256 * 1024;                // 1024*1024
    ushort_t* Qb   = WoT  + (size_t)1024 * 1024;               // 16*2048*64
    ushort_t* Kb   = Qb   + (size_t)NH * S_LEN * HD;           //  4*2048*64
    ushort_t* Vtb  = Kb   + (size_t)NKV * S_LEN * HD;          //  4*64*2048
    ushort_t* attnb= Vtb  + (size_t)NKV * HD * S_LEN;          // 2048*1024

    prep_kernel<<<dim3(16, 16, 5), 256, 0, stream>>>(x, xb, Wq, Wk, Wv, Wo,
                                                     WqT, WkT, WvT, WoT);
    gemm_qkv_mfma<<<dim3(32, 24), 256, 0, stream>>>(xb, WqT, WkT, WvT,
                                                    rc, rs, Qb, Kb, Vtb);
    attn_mfma<<<dim3(NH, 32), 256, 0, stream>>>(Qb, Kb, Vtb, attnb);
    gemm_out_mfma<<<dim3(32, 16), 256, 0, stream>>>(attnb, WoT, out);
}

// Round 6
// 140.118 us; speedup vs baseline: 2.3832x; 1.0194x over previous
//
#include <hip/hip_runtime.h>

typedef unsigned short ushort_t;
typedef __attribute__((ext_vector_type(8))) short short8;
typedef __attribute__((ext_vector_type(4))) float f32x4;
typedef __attribute__((ext_vector_type(4))) unsigned short ushort4v;
typedef __attribute__((ext_vector_type(8))) unsigned short ushort8v;

#define S_LEN 2048
#define D_MODEL 1024
#define NH 16
#define NKV 4
#define HD 64

// fp32 -> bf16 round-to-nearest-even
__device__ __forceinline__ ushort_t f2bf(float f) {
    unsigned u = __float_as_uint(f);
    u += 0x7fffu + ((u >> 16) & 1u);
    return (ushort_t)(u >> 16);
}

// async global->LDS, 16B/lane; LDS base wave-uniform, HW scatters lane*16
__device__ __forceinline__ void cp16(void* lds, const void* g) {
    __builtin_amdgcn_global_load_lds(
        (__attribute__((address_space(1))) void*)g,
        (__attribute__((address_space(3))) void*)lds, 16, 0, 0);
}

// ---------------------------------------------------------------------------
// Preprocess: z=0..3 -> weight transpose+cast W[k][n] fp32 -> WT[n][k] bf16;
// z=4 -> x fp32 -> bf16. grid (16,16,5).  (baseline verbatim)
// ---------------------------------------------------------------------------
__global__ __launch_bounds__(256) void prep_kernel(
    const float* __restrict__ x, ushort_t* __restrict__ xb,
    const float* __restrict__ Wq, const float* __restrict__ Wk,
    const float* __restrict__ Wv, const float* __restrict__ Wo,
    ushort_t* __restrict__ WqT, ushort_t* __restrict__ WkT,
    ushort_t* __restrict__ WvT, ushort_t* __restrict__ WoT)
{
    const int t = threadIdx.x;
    if (blockIdx.z == 4) {
        const int b  = blockIdx.y * 16 + blockIdx.x;
        const int i0 = (b * 256 + t) * 4;
        #pragma unroll
        for (int rep = 0; rep < 8; ++rep) {
            const int i = i0 + rep * 262144;   // 8 x 256K covers 2048*1024
            float4 v = *(const float4*)(x + i);
            ushort4v o = { f2bf(v.x), f2bf(v.y), f2bf(v.z), f2bf(v.w) };
            *(ushort4v*)(xb + i) = o;
        }
        return;
    }
    __shared__ ushort_t T[64 * 72];
    const float* W; ushort_t* WT; int N;
    switch (blockIdx.z) {
        case 0:  W = Wq; WT = WqT; N = 1024; break;
        case 1:  W = Wk; WT = WkT; N = 256;  break;
        case 2:  W = Wv; WT = WvT; N = 256;  break;
        default: W = Wo; WT = WoT; N = 1024; break;
    }
    const int n0 = blockIdx.y * 64;
    if (n0 >= N) return;
    const int k0 = blockIdx.x * 64;
    const int kr = t >> 4, nc = (t & 15) * 4;
    #pragma unroll
    for (int p = 0; p < 4; ++p) {
        const int k = kr + p * 16;
        float4 v = *(const float4*)(W + (size_t)(k0 + k) * N + n0 + nc);
        T[(nc + 0) * 72 + k] = f2bf(v.x);
        T[(nc + 1) * 72 + k] = f2bf(v.y);
        T[(nc + 2) * 72 + k] = f2bf(v.z);
        T[(nc + 3) * 72 + k] = f2bf(v.w);
    }
    __syncthreads();
    const int n = t >> 2, seg = (t & 3) * 16;
    ushort8v a = *(ushort8v*)&T[n * 72 + seg];
    ushort8v b = *(ushort8v*)&T[n * 72 + seg + 8];
    *(ushort8v*)(WT + (size_t)(n0 + n) * 1024 + k0 + seg)     = a;
    *(ushort8v*)(WT + (size_t)(n0 + n) * 1024 + k0 + seg + 8) = b;
}

// ---------------------------------------------------------------------------
// QKV projection, ROUND 6: 64x64 tile, grid (32,24)=768 (R5 balance kept),
// 4-deep circular LDS (64 KB) + counted vmcnt + raw s_barrier (T4).
// Per step: wait vmcnt(8) (loads issued 3 steps ago), barrier, stage tile
// k+3, compute tile k. Loads never drain to 0 in the main loop -- ~3 steps
// of compute hide the global->LDS latency that __syncthreads used to expose.
// Buffer lifecycle: write@k, read@k+3, rewrite@k+7 (3 barriers apart).
// ---------------------------------------------------------------------------
__global__ __launch_bounds__(256, 2) void gemm_qkv_mfma(
    const ushort_t* __restrict__ xb, const ushort_t* __restrict__ WqT,
    const ushort_t* __restrict__ WkT, const ushort_t* __restrict__ WvT,
    const float* __restrict__ rc, const float* __restrict__ rs,
    ushort_t* __restrict__ Qb, ushort_t* __restrict__ Kb,
    ushort_t* __restrict__ Vtb)
{
    __shared__ ushort_t As[4][64 * 64];    // 32 KB
    __shared__ ushort_t Bs[4][64 * 64];    // 32 KB

    const int t = threadIdx.x;
    const int lane = t & 63, wave = t >> 6;
    const int wr = wave >> 1, wc = wave & 1;
    const int quad = lane >> 4, l15 = lane & 15;
    const int lq = lane >> 3, lr = lane & 7;
    const int swz_st = (lr ^ lq) * 8;
    const int l7 = l15 & 7;
    const int fsw0 = (quad ^ l7) * 8;
    const int fsw1 = ((quad + 4) ^ l7) * 8;

    const int m0 = blockIdx.x * 64;
    const int cy = blockIdx.y;

    const ushort_t* WT; int nloc;
    if (cy < 16)      { WT = WqT; nloc = cy * 64; }
    else if (cy < 20) { WT = WkT; nloc = (cy - 16) * 64; }
    else              { WT = WvT; nloc = (cy - 20) * 64; }

    f32x4 acc[2][2];
    #pragma unroll
    for (int i = 0; i < 2; ++i)
        #pragma unroll
        for (int j = 0; j < 2; ++j) acc[i][j] = (f32x4)0.f;

    auto stage = [&](int buf, int k0) {
        #pragma unroll
        for (int i = 0; i < 2; ++i) {
            const int r = wave * 16 + i * 8 + lq;
            cp16(&As[buf][(wave * 16 + i * 8) * 64],
                 xb + (size_t)(m0 + r) * 1024 + k0 + swz_st);
            cp16(&Bs[buf][(wave * 16 + i * 8) * 64],
                 WT + (size_t)(nloc + r) * 1024 + k0 + swz_st);
        }
    };

    auto compute = [&](int cur) {
        const ushort_t* Ac = &As[cur][0];
        const ushort_t* Bc = &Bs[cur][0];
        #pragma unroll
        for (int h = 0; h < 2; ++h) {
            const int fsw = h ? fsw1 : fsw0;
            short8 av[2], bv[2];
            #pragma unroll
            for (int i = 0; i < 2; ++i)
                av[i] = *(const short8*)&Ac[(wr * 32 + i * 16 + l15) * 64 + fsw];
            #pragma unroll
            for (int j = 0; j < 2; ++j)   // interleaved cols wc*16 + j*32
                bv[j] = *(const short8*)&Bc[(wc * 16 + j * 32 + l15) * 64 + fsw];
            #pragma unroll
            for (int i = 0; i < 2; ++i)
                #pragma unroll
                for (int j = 0; j < 2; ++j)
                    acc[i][j] = __builtin_amdgcn_mfma_f32_16x16x32_bf16(
                        av[i], bv[j], acc[i][j], 0, 0, 0);
        }
    };

    stage(0, 0);
    stage(1, 64);
    stage(2, 128);

    for (int kk = 0; kk < 14; ++kk) {
        asm volatile("s_waitcnt vmcnt(8)" ::: "memory");
        __builtin_amdgcn_s_barrier();
        __builtin_amdgcn_sched_barrier(0);
        if (kk < 13) stage((kk + 3) & 3, (kk + 3) * 64);
        compute(kk & 3);
    }
    asm volatile("s_waitcnt vmcnt(4)" ::: "memory");
    __builtin_amdgcn_s_barrier();
    __builtin_amdgcn_sched_barrier(0);
    compute(2);                      // 14 & 3
    asm volatile("s_waitcnt vmcnt(0)" ::: "memory");
    __builtin_amdgcn_s_barrier();
    __builtin_amdgcn_sched_barrier(0);
    compute(3);                      // 15 & 3

    // epilogue: C/D layout col = l15, row = quad*4+reg (+16i)  [m89]
    // acc[i][0] -> head-local col d = wc*16+l15 (0..31); acc[i][1] -> d+32.
    if (cy < 20) {
        ushort_t* dst = (cy < 16) ? Qb : Kb;
        const int h = (cy < 16) ? cy : (cy - 16);
        const int d = wc * 16 + l15;
        #pragma unroll
        for (int i = 0; i < 2; ++i) {
            #pragma unroll
            for (int reg = 0; reg < 4; ++reg) {
                const int s = m0 + wr * 32 + i * 16 + quad * 4 + reg;
                const float c  = rc[s * 32 + d];
                const float sn = rs[s * 32 + d];
                const float v1 = acc[i][0][reg];    // x[d]
                const float v2 = acc[i][1][reg];    // x[d+32]
                dst[((size_t)h * S_LEN + s) * HD + d]      = f2bf(v1 * c - v2 * sn);
                dst[((size_t)h * S_LEN + s) * HD + d + 32] = f2bf(v2 * c + v1 * sn);
            }
        }
    } else {
        const int vh = cy - 20;
        #pragma unroll
        for (int i = 0; i < 2; ++i) {
            const int s0 = m0 + wr * 32 + i * 16 + quad * 4;
            #pragma unroll
            for (int j = 0; j < 2; ++j) {
                const int d = wc * 16 + j * 32 + l15;
                ushort4v o = { f2bf(acc[i][j][0]), f2bf(acc[i][j][1]),
                               f2bf(acc[i][j][2]), f2bf(acc[i][j][3]) };
                *(ushort4v*)&Vtb[((size_t)vh * HD + d) * S_LEN + s0] = o;
            }
        }
    }
}

// ---------------------------------------------------------------------------
// MFMA flash attention. grid (NH, 32), snake q-tile map (CU pairs ~17 rounds).
// BKV=128 per barrier round. Max-free softmax; one final shuffle-reduce.
// (144.23 baseline verbatim)
// ---------------------------------------------------------------------------
__global__ __launch_bounds__(256, 2) void attn_mfma(
    const ushort_t* __restrict__ Qb, const ushort_t* __restrict__ Kb,
    const ushort_t* __restrict__ Vtb, ushort_t* __restrict__ attnb)
{
    __shared__ ushort_t Ks[2][2][64 * 64];   // 32 KB [buf][sub][kv][d] swizzled
    __shared__ ushort_t Vs[2][2][64 * 64];   // 32 KB [buf][sub][d][kv] swizzled
    __shared__ ushort_t Ps[4][16 * 72];      // 9 KB wave-private P

    const int t = threadIdx.x;
    const int lane = t & 63, wave = t >> 6;
    const int quad = lane >> 4, l15 = lane & 15;
    const int lq = lane >> 3, lr = lane & 7;
    const int swz_st = (lr ^ lq) * 8;
    const int l7 = l15 & 7;
    const int fsw0 = (quad ^ l7) * 8;
    const int fsw1 = ((quad + 4) ^ l7) * 8;

    const int h  = blockIdx.x;
    const int y  = blockIdx.y;
    const int qt = (y < 16) ? y : 47 - y;
    const int q0 = qt * 64;
    const int kvh = h >> 2;
    const int qrow0 = q0 + wave * 16;

    const ushort_t* Qg = Qb + ((size_t)h * S_LEN + qrow0) * HD;
    const ushort_t* Kg = Kb + (size_t)kvh * S_LEN * HD;
    const ushort_t* Vg = Vtb + (size_t)kvh * HD * S_LEN;

    short8 aq0 = *(const short8*)(Qg + (size_t)l15 * HD + quad * 8);
    short8 aq1 = *(const short8*)(Qg + (size_t)l15 * HD + 32 + quad * 8);

    float ps4[4] = {0.f, 0.f, 0.f, 0.f};
    f32x4 Oacc[4];
    #pragma unroll
    for (int jb = 0; jb < 4; ++jb) Oacc[jb] = (f32x4)0.f;

    const int nround = (qt + 2) >> 1;   // rounds of 128 KV cols

    auto stage = [&](int buf, int kvbase) {
        #pragma unroll
        for (int u = 0; u < 2; ++u)
            #pragma unroll
            for (int i = 0; i < 2; ++i) {
                const int r = wave * 16 + i * 8 + lq;
                cp16(&Ks[buf][u][(wave * 16 + i * 8) * 64],
                     Kg + (size_t)(kvbase + u * 64 + r) * 64 + swz_st);
                cp16(&Vs[buf][u][(wave * 16 + i * 8) * 64],
                     Vg + (size_t)r * 2048 + kvbase + u * 64 + swz_st);
            }
    };

    stage(0, 0);
    __syncthreads();

    ushort_t* Pw = &Ps[wave][0];

    for (int round = 0; round < nround; ++round) {
        const int cur = round & 1;
        if (round + 1 < nround) stage(cur ^ 1, (round + 1) * 128);

        #pragma unroll
        for (int u = 0; u < 2; ++u) {
            const int kv0 = round * 128 + u * 64;
            if (kv0 > q0 + 63) break;        // fully masked sub-tile
            const ushort_t* Kc = &Ks[cur][u][0];
            const ushort_t* Vc = &Vs[cur][u][0];

            // S = Q K^T
            f32x4 sv[4];
            #pragma unroll
            for (int jb = 0; jb < 4; ++jb) {
                short8 b0 = *(const short8*)&Kc[(jb * 16 + l15) * 64 + fsw0];
                short8 b1 = *(const short8*)&Kc[(jb * 16 + l15) * 64 + fsw1];
                f32x4 z = (f32x4)0.f;
                z = __builtin_amdgcn_mfma_f32_16x16x32_bf16(aq0, b0, z, 0, 0, 0);
                z = __builtin_amdgcn_mfma_f32_16x16x32_bf16(aq1, b1, z, 0, 0, 0);
                sv[jb] = z;
            }

            // max-free softmax: P = exp(s/8); mask only on the diagonal sub-tile
            const bool diag = (kv0 == q0);
            #pragma unroll
            for (int jb = 0; jb < 4; ++jb) {
                const int col = kv0 + jb * 16 + l15;
                #pragma unroll
                for (int reg = 0; reg < 4; ++reg) {
                    float e = __expf(sv[jb][reg] * 0.125f);
                    if (diag && col > qrow0 + quad * 4 + reg) e = 0.f;
                    sv[jb][reg] = e;
                    ps4[reg] += e;
                }
            }

            // P: C-layout -> wave-private LDS -> A-layout frags  [m120]
            #pragma unroll
            for (int jb = 0; jb < 4; ++jb)
                #pragma unroll
                for (int reg = 0; reg < 4; ++reg)
                    Pw[(quad * 4 + reg) * 72 + jb * 16 + l15] = f2bf(sv[jb][reg]);
            short8 p0 = *(const short8*)&Pw[l15 * 72 + quad * 8];
            short8 p1 = *(const short8*)&Pw[l15 * 72 + 32 + quad * 8];

            // O += P V
            #pragma unroll
            for (int jb = 0; jb < 4; ++jb) {
                short8 v0 = *(const short8*)&Vc[(jb * 16 + l15) * 64 + fsw0];
                short8 v1 = *(const short8*)&Vc[(jb * 16 + l15) * 64 + fsw1];
                Oacc[jb] = __builtin_amdgcn_mfma_f32_16x16x32_bf16(p0, v0, Oacc[jb], 0, 0, 0);
                Oacc[jb] = __builtin_amdgcn_mfma_f32_16x16x32_bf16(p1, v1, Oacc[jb], 0, 0, 0);
            }
        }

        __syncthreads();   // drain stage(round+1), guard buffer reuse
    }

    // final row-sum reduction + normalize + store
    #pragma unroll
    for (int reg = 0; reg < 4; ++reg) {
        float l = ps4[reg];
        l += __shfl_xor(l, 1);
        l += __shfl_xor(l, 2);
        l += __shfl_xor(l, 4);
        l += __shfl_xor(l, 8);
        const float inv = 1.f / l;
        const int s = qrow0 + quad * 4 + reg;
        #pragma unroll
        for (int jb = 0; jb < 4; ++jb)
            attnb[(size_t)s * D_MODEL + h * HD + jb * 16 + l15] =
                f2bf(Oacc[jb][reg] * inv);
    }
}

// ---------------------------------------------------------------------------
// Output projection, ROUND 6: same T4 transformation as qkv. 64x64 tile,
// grid (32,16)=512 blocks (2/CU), 4-deep circular LDS (64 KB), counted vmcnt.
// ---------------------------------------------------------------------------
__global__ __launch_bounds__(256, 2) void gemm_out_mfma(
    const ushort_t* __restrict__ Ab, const ushort_t* __restrict__ WoT,
    float* __restrict__ out)
{
    __shared__ ushort_t As[4][64 * 64];    // 32 KB
    __shared__ ushort_t Bs[4][64 * 64];    // 32 KB

    const int t = threadIdx.x;
    const int lane = t & 63, wave = t >> 6;
    const int wr = wave >> 1, wc = wave & 1;
    const int quad = lane >> 4, l15 = lane & 15;
    const int lq = lane >> 3, lr = lane & 7;
    const int swz_st = (lr ^ lq) * 8;
    const int l7 = l15 & 7;
    const int fsw0 = (quad ^ l7) * 8;
    const int fsw1 = ((quad + 4) ^ l7) * 8;

    const int m0 = blockIdx.x * 64;
    const int n0 = blockIdx.y * 64;

    f32x4 acc[2][2];
    #pragma unroll
    for (int i = 0; i < 2; ++i)
        #pragma unroll
        for (int j = 0; j < 2; ++j) acc[i][j] = (f32x4)0.f;

    auto stage = [&](int buf, int k0) {
        #pragma unroll
        for (int i = 0; i < 2; ++i) {
            const int r = wave * 16 + i * 8 + lq;
            cp16(&As[buf][(wave * 16 + i * 8) * 64],
                 Ab + (size_t)(m0 + r) * 1024 + k0 + swz_st);
            cp16(&Bs[buf][(wave * 16 + i * 8) * 64],
                 WoT + (size_t)(n0 + r) * 1024 + k0 + swz_st);
        }
    };

    auto compute = [&](int cur) {
        const ushort_t* Ac = &As[cur][0];
        const ushort_t* Bc = &Bs[cur][0];
        #pragma unroll
        for (int h = 0; h < 2; ++h) {
            const int fsw = h ? fsw1 : fsw0;
            short8 av[2], bv[2];
            #pragma unroll
            for (int i = 0; i < 2; ++i)
                av[i] = *(const short8*)&Ac[(wr * 32 + i * 16 + l15) * 64 + fsw];
            #pragma unroll
            for (int j = 0; j < 2; ++j)
                bv[j] = *(const short8*)&Bc[(wc * 32 + j * 16 + l15) * 64 + fsw];
            #pragma unroll
            for (int i = 0; i < 2; ++i)
                #pragma unroll
                for (int j = 0; j < 2; ++j)
                    acc[i][j] = __builtin_amdgcn_mfma_f32_16x16x32_bf16(
                        av[i], bv[j], acc[i][j], 0, 0, 0);
        }
    };

    stage(0, 0);
    stage(1, 64);
    stage(2, 128);

    for (int kk = 0; kk < 14; ++kk) {
        asm volatile("s_waitcnt vmcnt(8)" ::: "memory");
        __builtin_amdgcn_s_barrier();
        __builtin_amdgcn_sched_barrier(0);
        if (kk < 13) stage((kk + 3) & 3, (kk + 3) * 64);
        compute(kk & 3);
    }
    asm volatile("s_waitcnt vmcnt(4)" ::: "memory");
    __builtin_amdgcn_s_barrier();
    __builtin_amdgcn_sched_barrier(0);
    compute(2);                      // 14 & 3
    asm volatile("s_waitcnt vmcnt(0)" ::: "memory");
    __builtin_amdgcn_s_barrier();
    __builtin_amdgcn_sched_barrier(0);
    compute(3);                      // 15 & 3

    #pragma unroll
    for (int i = 0; i < 2; ++i)
        #pragma unroll
        for (int reg = 0; reg < 4; ++reg) {
            const int s = m0 + wr * 32 + i * 16 + quad * 4 + reg;
            #pragma unroll
            for (int j = 0; j < 2; ++j)
                out[(size_t)s * D_MODEL + n0 + wc * 32 + j * 16 + l15] = acc[i][j][reg];
        }
}

// ---------------------------------------------------------------------------
extern "C" void kernel_launch(void* const* d_in, const int* in_sizes, int n_in,
                              void* d_out, int out_size, void* d_ws, size_t ws_size,
                              hipStream_t stream)
{
    const float* x  = (const float*)d_in[0];
    const float* rc = (const float*)d_in[1];
    const float* rs = (const float*)d_in[2];
    const float* Wq = (const float*)d_in[3];
    const float* Wk = (const float*)d_in[4];
    const float* Wv = (const float*)d_in[5];
    const float* Wo = (const float*)d_in[6];
    float* out = (float*)d_out;

    ushort_t* xb   = (ushort_t*)d_ws;                          // 2048*1024
    ushort_t* WqT  = xb   + (size_t)2048 * 1024;               // 1024*1024
    ushort_t* WkT  = WqT  + (size_t)1024 * 1024;               //  256*1024
    ushort_t* WvT  = WkT  + (size_t)256 * 1024;                //  256*1024
    ushort_t* WoT  = WvT  + (size_t)256 * 1024;                // 1024*1024
    ushort_t* Qb   = WoT  + (size_t)1024 * 1024;               // 16*2048*64
    ushort_t* Kb   = Qb   + (size_t)NH * S_LEN * HD;           //  4*2048*64
    ushort_t* Vtb  = Kb   + (size_t)NKV * S_LEN * HD;          //  4*64*2048
    ushort_t* attnb= Vtb  + (size_t)NKV * HD * S_LEN;          // 2048*1024

    prep_kernel<<<dim3(16, 16, 5), 256, 0, stream>>>(x, xb, Wq, Wk, Wv, Wo,
                                                     WqT, WkT, WvT, WoT);
    gemm_qkv_mfma<<<dim3(32, 24), 256, 0, stream>>>(xb, WqT, WkT, WvT,
                                                    rc, rs, Qb, Kb, Vtb);
    attn_mfma<<<dim3(NH, 32), 256, 0, stream>>>(Qb, Kb, Vtb, attnb);
    gemm_out_mfma<<<dim3(32, 16), 256, 0, stream>>>(attnb, WoT, out);
}